// Round 3
// baseline (530.710 us; speedup 1.0000x reference)
//
#include <hip/hip_runtime.h>
#include <hip/hip_bf16.h>

#define BB 128
#define NN 2048
#define DD 128
#define HH 8

// ws layout (float offsets)
#define GSUM_OFF 0            // B*D = 16384 (zeroed)
#define ESUM_OFF 16384        // B*H = 1024 (zeroed)
#define WQE_OFF  17408        // B*H*D = 131072
#define SB_OFF   148480       // B*H = 1024
#define P_OFF    149504       // 128*384 = 49152
#define PB_OFF   198656       // 128
#define TT_OFF   198784       // 8*384*128 = 393216
#define UU_OFF   592000       // 8*128 = 1024
#define SBS_OFF  593024       // 8*384 = 3072
#define SBC_OFF  596096       // 8
#define E_OFF    596608       // B*H*N = 2097152

// ---------- K1: gsum[b][d] = sum_n x[b][n][d] (float4 + shfl + LDS reduce) ----------
__launch_bounds__(256)
__global__ void k1_gsum(const float* __restrict__ x, float* __restrict__ gsum) {
    int b = blockIdx.y, cx = blockIdx.x, t = threadIdx.x;
    int c4 = t & 31, rg = t >> 5;
    const float4* x4 = (const float4*)(x + ((size_t)b * NN + cx * 256) * DD);
    float4 acc = make_float4(0.f, 0.f, 0.f, 0.f);
    #pragma unroll 8
    for (int i = 0; i < 32; ++i) {
        float4 v = x4[(size_t)(rg + 8 * i) * 32 + c4];
        acc.x += v.x; acc.y += v.y; acc.z += v.z; acc.w += v.w;
    }
    // combine lane pairs rg even/odd within wave
    acc.x += __shfl_xor(acc.x, 32, 64);
    acc.y += __shfl_xor(acc.y, 32, 64);
    acc.z += __shfl_xor(acc.z, 32, 64);
    acc.w += __shfl_xor(acc.w, 32, 64);
    __shared__ float xsum[4][32][4];
    int w = t >> 6, lane = t & 63;
    if (lane < 32) {
        xsum[w][lane][0] = acc.x; xsum[w][lane][1] = acc.y;
        xsum[w][lane][2] = acc.z; xsum[w][lane][3] = acc.w;
    }
    __syncthreads();
    if (t < 32) {
        #pragma unroll
        for (int comp = 0; comp < 4; ++comp) {
            float s = xsum[0][t][comp] + xsum[1][t][comp] + xsum[2][t][comp] + xsum[3][t][comp];
            atomicAdd(&gsum[b * DD + t * 4 + comp], s);
        }
    }
}

// ---------- K2a1: P = Wq @ Wl (128x384), pb = Wq@bl + bq ----------
__global__ void k2a1(const float* __restrict__ Wq, const float* __restrict__ Wl,
                     const float* __restrict__ bl, const float* __restrict__ bq,
                     float* ws) {
    __shared__ float wqL[128];
    int m = blockIdx.x, t = threadIdx.x;   // 384 threads
    if (t < 128) wqL[t] = Wq[m * 128 + t];
    __syncthreads();
    float acc = 0.f;
    #pragma unroll 8
    for (int r = 0; r < 128; ++r) acc = fmaf(wqL[r], Wl[(size_t)r * 384 + t], acc);
    ws[P_OFF + (size_t)m * 384 + t] = acc;
    if (t == 0) {
        float pb = bq[m];
        for (int r = 0; r < 128; ++r) pb = fmaf(wqL[r], bl[r], pb);
        ws[PB_OFF + m] = pb;
    }
}

// ---------- K2a2: Tt[h][e][d] = 0.25*sum_j Wk[h16+j][d]*P[h16+j][e]; u, sbS, sbc ----------
__global__ void k2a2(const float* __restrict__ Wk, const float* __restrict__ bk, float* ws) {
    __shared__ float PL[16 * 33];
    __shared__ float WkL[16 * 128];
    __shared__ float pbL[16], bkL[16];
    int ecb = blockIdx.x, h = blockIdx.y, t = threadIdx.x;  // 128 threads
    int e0 = ecb * 32;
    const float* P = ws + P_OFF;
    for (int i = t; i < 512; i += 128) {
        int j = i >> 5, ec = i & 31;
        PL[j * 33 + ec] = P[(size_t)(h * 16 + j) * 384 + e0 + ec];
    }
    for (int i = t; i < 2048; i += 128) WkL[i] = Wk[(size_t)h * 16 * 128 + i];
    if (t < 16) { pbL[t] = ws[PB_OFF + h * 16 + t]; bkL[t] = bk[h * 16 + t]; }
    __syncthreads();
    int d = t;
    for (int ec = 0; ec < 32; ++ec) {
        float s = 0.f;
        #pragma unroll
        for (int j = 0; j < 16; ++j) s = fmaf(WkL[j * 128 + d], PL[j * 33 + ec], s);
        ws[TT_OFF + ((size_t)h * 384 + e0 + ec) * 128 + d] = 0.25f * s;
    }
    if (ecb == 0) {
        float s = 0.f;
        #pragma unroll
        for (int j = 0; j < 16; ++j) s = fmaf(WkL[j * 128 + d], pbL[j], s);
        ws[UU_OFF + h * 128 + d] = 0.25f * s;
    }
    if (t < 32) {
        float s = 0.f;
        #pragma unroll
        for (int j = 0; j < 16; ++j) s = fmaf(bkL[j], PL[j * 33 + t], s);
        ws[SBS_OFF + h * 384 + e0 + t] = 0.25f * s;
    }
    if (ecb == 0 && t == 0) {
        float s = 0.f;
        for (int j = 0; j < 16; ++j) s = fmaf(bkL[j], pbL[j], s);
        ws[SBC_OFF + h] = 0.25f * s;
    }
}

// ---------- K2b: ctx_b gather; wqe[b][h][d] = Tt[h]·ctx_b + u; sb[b][h] ----------
__launch_bounds__(256)
__global__ void k2b(const float* __restrict__ x,
                    const int* __restrict__ fn_p, const int* __restrict__ cn_p,
                    float* ws) {
    __shared__ float ctxL[384];
    int hp = blockIdx.x, b = blockIdx.y, t = threadIdx.x;  // 256 threads
    bool is64 = (fn_p[1] == 0 && fn_p[3] == 0 && fn_p[5] == 0 && fn_p[7] == 0 &&
                 cn_p[1] == 0 && cn_p[3] == 0 && cn_p[5] == 0 && cn_p[7] == 0);
    int fn = is64 ? fn_p[2 * b] : fn_p[b];
    int cn = is64 ? cn_p[2 * b] : cn_p[b];
    const float* gsum = ws + GSUM_OFF;
    if (t < 128) {
        ctxL[t]       = gsum[b * DD + t] * (1.0f / NN);
        ctxL[256 + t] = x[((size_t)b * NN + cn) * DD + t];
    } else {
        int u = t - 128;
        ctxL[128 + u] = x[((size_t)b * NN + fn) * DD + u];
    }
    __syncthreads();
    int h = hp * 2 + (t >> 7), d = t & 127;
    float acc = ws[UU_OFF + h * 128 + d];
    const float* T = ws + TT_OFF + (size_t)h * 384 * 128 + d;
    #pragma unroll 8
    for (int e = 0; e < 384; ++e) acc = fmaf(T[(size_t)e * 128], ctxL[e], acc);
    ws[WQE_OFF + (size_t)b * 1024 + h * 128 + d] = acc;
    if (hp == 0 && t < 8) {
        float s = ws[SBC_OFF + t];
        const float* S = ws + SBS_OFF + t * 384;
        for (int e = 0; e < 384; ++e) s = fmaf(S[e], ctxL[e], s);
        ws[SB_OFF + b * HH + t] = s;
    }
}

// mask layout: 0 = byte (np.bool_), 1 = int32, 2 = int64
__device__ __forceinline__ int detect_mask_kind(const int* mw) {
    int big = 0, oddnz = 0;
    #pragma unroll 8
    for (int i = 0; i < 64; ++i) {
        unsigned w = (unsigned)mw[i];
        if (w > 1u) big = 1;
        if ((i & 1) && w != 0u) oddnz = 1;
    }
    return big ? 0 : (oddnz ? 1 : 2);
}
__device__ __forceinline__ int mask_at(const unsigned char* mb, const int* mw, int kind, size_t idx) {
    if (kind == 0) return mb[idx];
    if (kind == 1) return mw[idx];
    return mw[2 * idx];
}

// ---------- K3r: e[b][h][n] = mask ? 0 : exp(x[b,n]·wqe[b,h] + sb); x -> registers ----------
__launch_bounds__(256)
__global__ void k3r(const float* __restrict__ x, const void* __restrict__ mask,
                    const float* __restrict__ ws_ro,
                    float* __restrict__ wse, float* __restrict__ esum) {
    __shared__ float wqL[1024];
    __shared__ float sbL[8];
    int b = blockIdx.y, cx = blockIdx.x, t = threadIdx.x;  // grid (4, B), 256 thr
    const float* wqe = ws_ro + WQE_OFF + (size_t)b * 1024;
    for (int i = t; i < 1024; i += 256) wqL[i] = wqe[i];
    if (t < 8) sbL[t] = (ws_ro + SB_OFF)[b * HH + t];
    __syncthreads();

    const unsigned char* mb = (const unsigned char*)mask;
    const int* mw = (const int*)mask;
    int mkind = detect_mask_kind(mw);

    int n0 = cx * 512 + t, n1 = n0 + 256;
    float accA[8], accB[8];
    #pragma unroll
    for (int h = 0; h < HH; ++h) { accA[h] = sbL[h]; accB[h] = sbL[h]; }

    const float4* xA = (const float4*)(x + ((size_t)b * NN + n0) * DD);
    const float4* xB = (const float4*)(x + ((size_t)b * NN + n1) * DD);

    #pragma unroll
    for (int p = 0; p < 4; ++p) {
        float4 a[8], c[8];
        #pragma unroll
        for (int q = 0; q < 8; ++q) { a[q] = xA[p * 8 + q]; c[q] = xB[p * 8 + q]; }
        #pragma unroll
        for (int h = 0; h < HH; ++h) {
            const float4* w4 = (const float4*)&wqL[h * 128 + p * 32];
            #pragma unroll
            for (int q = 0; q < 8; ++q) {
                float4 w = w4[q];
                accA[h] += a[q].x * w.x + a[q].y * w.y + a[q].z * w.z + a[q].w * w.w;
                accB[h] += c[q].x * w.x + c[q].y * w.y + c[q].z * w.z + c[q].w * w.w;
            }
        }
    }

    size_t mbase = (size_t)b * NN;
    int m0 = mask_at(mb, mw, mkind, mbase + n0);
    int m1 = mask_at(mb, mw, mkind, mbase + n1);
    float eA[8], eB[8];
    #pragma unroll
    for (int h = 0; h < HH; ++h) {
        eA[h] = m0 ? 0.f : __expf(accA[h]);
        eB[h] = m1 ? 0.f : __expf(accB[h]);
        wse[((size_t)(b * HH + h)) * NN + n0] = eA[h];
        wse[((size_t)(b * HH + h)) * NN + n1] = eB[h];
    }
    int lane = t & 63;
    #pragma unroll
    for (int h = 0; h < HH; ++h) {
        float v = eA[h] + eB[h];
        #pragma unroll
        for (int off = 32; off >= 1; off >>= 1) v += __shfl_xor(v, off, 64);
        if (lane == 0) atomicAdd(&esum[b * HH + h], v);
    }
}

// ---------- K4: out[b][n] = sum_h e[b][h][n] * (0.125/esum[b][h]) ----------
__global__ void k4_out(const float* __restrict__ wse, const float* __restrict__ esum,
                       float* __restrict__ out) {
    __shared__ float rinv[8];
    int b = blockIdx.y, cx = blockIdx.x, t = threadIdx.x;
    if (t < 8) rinv[t] = 0.125f / esum[b * HH + t];
    __syncthreads();
    int n = cx * 256 + t;
    float o = 0.f;
    #pragma unroll
    for (int h = 0; h < HH; ++h)
        o += wse[((size_t)(b * HH + h)) * NN + n] * rinv[h];
    out[(size_t)b * NN + n] = o;
}

extern "C" void kernel_launch(void* const* d_in, const int* in_sizes, int n_in,
                              void* d_out, int out_size, void* d_ws, size_t ws_size,
                              hipStream_t stream) {
    const float* x  = (const float*)d_in[0];
    const int* fn   = (const int*)d_in[1];
    const int* cn   = (const int*)d_in[2];
    const void* mk  = d_in[3];
    const float* Wl = (const float*)d_in[4];
    const float* bl = (const float*)d_in[5];
    const float* Wq = (const float*)d_in[6];
    const float* bq = (const float*)d_in[7];
    const float* Wk = (const float*)d_in[8];
    const float* bk = (const float*)d_in[9];
    float* ws  = (float*)d_ws;
    float* out = (float*)d_out;

    // zero gsum + esum accumulators
    hipMemsetAsync(d_ws, 0, (size_t)(16384 + 1024) * 4, stream);

    k1_gsum<<<dim3(8, BB), 256, 0, stream>>>(x, ws + GSUM_OFF);
    k2a1<<<128, 384, 0, stream>>>(Wq, Wl, bl, bq, ws);
    k2a2<<<dim3(12, HH), 128, 0, stream>>>(Wk, bk, ws);
    k2b<<<dim3(4, BB), 256, 0, stream>>>(x, fn, cn, ws);
    k3r<<<dim3(4, BB), 256, 0, stream>>>(x, mk, ws, ws + E_OFF, ws + ESUM_OFF);
    k4_out<<<dim3(8, BB), 256, 0, stream>>>(ws + E_OFF, ws + ESUM_OFF, out);
}